// Round 8
// baseline (794.211 us; speedup 1.0000x reference)
//
#include <hip/hip_runtime.h>
#include <cstdint>
#include <cstddef>

#define NROWS 16384
#define KDIM  16384
#define EPSF  1e-7f
#define MINN  1e-15f
#define MAXN  1e6f
/* matmul1 (f32 adj): BK=64 */
#define BM    32
#define BK2   64
#define NSTEP2 (KDIM/BK2)      /* 256 */
#define APG   528              /* A page: 32 rows*16B + 16 pad */
#define BPG   1040             /* B page: 64 cols*16B + 16 pad */
#define AB1   (8*APG)          /* 4224 */
#define BB1   (8*BPG)          /* 8320 */
/* matmul2 (bf16 adj): BK=128 */
#define BKB   128
#define NSTEPB (KDIM/BKB)      /* 128 */
#define AB2   (16*APG)         /* 8448 */
#define BB2   (16*BPG)         /* 16640 */

typedef __attribute__((ext_vector_type(8))) short short8;
typedef __attribute__((ext_vector_type(4))) float f32x4;
typedef __attribute__((ext_vector_type(4))) unsigned short u16x4;

__device__ __forceinline__ unsigned short f2bf(float f){
  union { float f; unsigned u; } c; c.f = f;
  unsigned u = c.u;
  unsigned r = (u + 0x7FFFu + ((u >> 16) & 1u)) >> 16;   // RNE
  return (unsigned short)r;
}

__device__ __forceinline__ float wredsum(float v){
  v += __shfl_xor(v, 1);
  v += __shfl_xor(v, 2);
  v += __shfl_xor(v, 4);
  v += __shfl_xor(v, 8);
  v += __shfl_xor(v, 16);
  v += __shfl_xor(v, 32);
  return v;
}

// ---- ub = logmap0(proj(expmap0(proj_tan0(b)))) for b1 (wave0) and b2 (wave1)
__global__ __launch_bounds__(128) void k_bias(const float* __restrict__ b1,
                                              const float* __restrict__ b2,
                                              float* __restrict__ ub){
  int w = threadIdx.x >> 6, l = threadIdx.x & 63;
  const float* b = w ? b2 : b1;
  float bv = b[l];
  float tb = l ? bv : 0.f;
  float s  = wredsum(tb*tb);
  float xn = fmaxf(sqrtf(s), MINN);
  float sc = sinhf(xn)/xn;
  float e  = sc*tb;
  float s2 = wredsum(e*e);
  float x0 = sqrtf(fmaxf(1.f+s2, EPSF));
  float yn = fmaxf(sqrtf(s2), MINN);
  float th = fmaxf(x0, 1.f+EPSF);
  float u  = l ? acoshf(th)*e/yn : 0.f;
  ub[w*64 + l] = u;
}

// ---- per-row linear + mobius bias chain -> g
template<int MODE>
__global__ __launch_bounds__(256) void k_linear(const float* __restrict__ in,
                                                const float* __restrict__ W,
                                                const float* __restrict__ ub,
                                                float* __restrict__ g){
  __shared__ float Wt[64*65];
  int tid = threadIdx.x;
  for(int idx = tid; idx < 4096; idx += 256){
    int j = idx >> 6, k = idx & 63;
    Wt[k*65 + j] = W[idx];
  }
  __syncthreads();
  int lane = tid & 63;
  int row  = blockIdx.x*4 + (tid >> 6);
  float v = in[(size_t)row*64 + lane];
  float lx;
  if (MODE == 0){
    float t  = lane ? v : 0.f;
    float s  = wredsum(t*t);
    float tn = fmaxf(sqrtf(s), MINN);
    float sc = sinhf(tn)/tn;
    float e  = sc*t;
    float s2 = wredsum(e*e);
    float x0 = sqrtf(fmaxf(1.f+s2, EPSF));
    float yn = fmaxf(sqrtf(s2), MINN);
    float th = fmaxf(x0, 1.f+EPSF);
    lx = lane ? acoshf(th)*e/yn : 0.f;
  } else {
    float t  = lane ? v : 0.f;
    float s2 = wredsum(t*t);
    float x0 = __shfl(v, 0);
    float yn = fmaxf(sqrtf(s2), MINN);
    float th = fmaxf(x0, 1.f+EPSF);
    lx = lane ? acoshf(th)*t/yn : 0.f;
  }
  float mv = 0.f;
  #pragma unroll
  for(int k = 0; k < 64; k++){
    mv = fmaf(__shfl(lx, k), Wt[k*65 + lane], mv);
  }
  float u  = lane ? mv : 0.f;
  float s  = wredsum(u*u);
  float un = fmaxf(sqrtf(s), MINN);
  float sc = sinhf(un)/un;
  float e  = sc*u;
  float s2 = wredsum(e*e);
  float r0 = sqrtf(fmaxf(1.f+s2, EPSF));
  float ubt   = lane ? ub[lane] : 0.f;
  float yn    = fmaxf(sqrtf(s2), MINN);
  float yhat  = e/yn;
  float alpha = wredsum(yhat*ubt);
  float w     = ubt - alpha*(1.f - r0)*yhat;
  float ux    = wredsum(e*w);
  float v0    = ux / fmaxf(r0, EPSF);
  float md    = wredsum(w*w) - v0*v0;
  float normu = fminf(sqrtf(fmaxf(md, EPSF)), MAXN);
  float th2   = fmaxf(normu, MINN);
  float ch    = coshf(th2);
  float shq   = sinhf(th2)/th2;
  float ov    = ch*(lane ? e : r0) + shq*(lane ? w : v0);
  float ot    = lane ? ov : 0.f;
  float s3    = wredsum(ot*ot);
  float o0    = sqrtf(fmaxf(1.f+s3, EPSF));
  float yn2 = fmaxf(sqrtf(s3), MINN);
  float th3 = fmaxf(o0, 1.f+EPSF);
  float gv  = lane ? acoshf(th3)*ot/yn2 : 0.f;
  g[(size_t)row*64 + lane] = gv;
}

// ---- transpose + bf16 convert: g[N][64] f32 -> gT[64][N] bf16
__global__ __launch_bounds__(256) void k_tr(const float* __restrict__ g,
                                            short* __restrict__ gT){
  __shared__ float t[64][65];
  int tid = threadIdx.x;
  int b   = blockIdx.x;
  int r   = tid >> 2;
  int c0  = (tid & 3)*16;
  const float* src = g + ((size_t)b*64 + r)*64 + c0;
  #pragma unroll
  for(int i = 0; i < 4; i++){
    float4 v = *(const float4*)(src + i*4);
    t[r][c0 + i*4 + 0] = v.x; t[r][c0 + i*4 + 1] = v.y;
    t[r][c0 + i*4 + 2] = v.z; t[r][c0 + i*4 + 3] = v.w;
  }
  __syncthreads();
  int n   = tid >> 2;
  int seg = tid & 3;
  short8 p0, p1;
  #pragma unroll
  for(int j = 0; j < 8; j++) p0[j] = (short)f2bf(t[seg*16 + j][n]);
  #pragma unroll
  for(int j = 0; j < 8; j++) p1[j] = (short)f2bf(t[seg*16 + 8 + j][n]);
  short* dst = gT + (size_t)n*KDIM + b*64 + seg*16;
  *(short8*)(dst)     = p0;
  *(short8*)(dst + 8) = p1;
}

// ---- LAYER-1 matmul: full-K, f32 adj in, double-buffered LDS (R5-proven base);
// additionally streams the bf16-converted adj tile to adjBF (global) for layer 2.
__global__ __launch_bounds__(512) void k_matmul1(const float* __restrict__ adj,
                                                 const short* __restrict__ gT,
                                                 float* __restrict__ agg,
                                                 float* __restrict__ prsum,
                                                 short* __restrict__ adjBF){
  __shared__ __align__(16) char lds[2*(AB1 + BB1)];   // ~25 KB
  int tid  = threadIdx.x;
  int lane = tid & 63, w = tid >> 6;
  int row0 = blockIdx.x * BM;

  // A staging: thread -> (row r, k-quad kq); coalesced float4
  int r  = tid >> 4;                 // 0..31
  int kq = tid & 15;                 // 16 quads = 64 k
  const float* ap = adj + (size_t)(row0 + r)*KDIM + kq*4;
  short* abf = adjBF + (size_t)(row0 + r)*KDIM + kq*4;
  int AwOff = (kq >> 1)*APG + r*16 + (kq & 1)*8;

  // B staging: thread -> (col nB, k-octet q2); contiguous short8 from gT row
  int nB = tid & 63;
  int q2 = tid >> 6;                 // 0..7
  const short* bp = gT + (size_t)nB*KDIM + q2*8;
  int BwOff = q2*BPG + nB*16;

  // fragment roles: wave (wm,wn): rows wm*16..+16, cols wn*16..+16
  int wm = w >> 2, wn = w & 3;
  int fr = lane & 15, fk = lane >> 4;
  int ArdOff = fk*APG + (wm*16 + fr)*16;
  int BrdOff = fk*BPG + (wn*16 + fr)*16;

  f32x4 acc = {0.f,0.f,0.f,0.f};
  float rs = 0.f;

  // prologue: stage step 0, preload step 1
  float4 a0 = *(const float4*)(ap);
  short8 b0 = *(const short8*)(bp);
  rs += a0.x + a0.y + a0.z + a0.w;
  u16x4 ak0 = { f2bf(a0.x), f2bf(a0.y), f2bf(a0.z), f2bf(a0.w) };
  *(u16x4*)(lds + AwOff) = ak0;
  *(short8*)(lds + 2*AB1 + BwOff - 2*AB1 + 2*AB1) = b0;   // B buf0
  *(u16x4*)(abf) = ak0;                                   // adjBF step 0
  float4 aR = *(const float4*)(ap + BK2);
  short8 bR = *(const short8*)(bp + BK2);
  rs += aR.x + aR.y + aR.z + aR.w;
  __syncthreads();

  for (int i = 0; i < NSTEP2; i++){
    const char* Ab = lds + (i & 1)*AB1;
    const char* Bb = lds + 2*AB1 + (i & 1)*BB1;
    short8 af0 = *(const short8*)(Ab + ArdOff);
    short8 af1 = *(const short8*)(Ab + ArdOff + 4*APG);
    short8 bf0 = *(const short8*)(Bb + BrdOff);
    short8 bf1 = *(const short8*)(Bb + BrdOff + 4*BPG);
    float4 aN; short8 bN;
    if (i + 2 < NSTEP2){
      aN = *(const float4*)(ap + (size_t)(i+2)*BK2);
      bN = *(const short8*)(bp + (size_t)(i+2)*BK2);
      rs += aN.x + aN.y + aN.z + aN.w;
    }
    acc = __builtin_amdgcn_mfma_f32_16x16x32_bf16(af0, bf0, acc, 0, 0, 0);
    acc = __builtin_amdgcn_mfma_f32_16x16x32_bf16(af1, bf1, acc, 0, 0, 0);
    if (i + 1 < NSTEP2){
      char* Aw = lds + ((i+1) & 1)*AB1;
      char* Bw = lds + 2*AB1 + ((i+1) & 1)*BB1;
      u16x4 ak = { f2bf(aR.x), f2bf(aR.y), f2bf(aR.z), f2bf(aR.w) };
      *(u16x4*)(Aw + AwOff) = ak;
      *(short8*)(Bw + BwOff) = bR;
      *(u16x4*)(abf + (size_t)(i+1)*BK2) = ak;            // adjBF step i+1
      aR = aN; bR = bN;
    }
    __syncthreads();
  }

  rs += __shfl_xor(rs, 1);
  rs += __shfl_xor(rs, 2);
  rs += __shfl_xor(rs, 4);
  rs += __shfl_xor(rs, 8);
  if ((lane & 15) == 0) prsum[row0 + r] = rs;   // r = w*4 + (lane>>4)

  float* ob = agg + (size_t)(row0 + wm*16)*64 + wn*16;
  #pragma unroll
  for(int q = 0; q < 4; q++){
    ob[(size_t)((lane >> 4)*4 + q)*64 + (lane & 15)] = acc[q];
  }
}

// ---- LAYER-2 matmul: full-K, bf16 adjBF in (half the read bytes), BK=128
__global__ __launch_bounds__(512) void k_matmul2(const short* __restrict__ adjBF,
                                                 const short* __restrict__ gT,
                                                 float* __restrict__ agg){
  __shared__ __align__(16) char lds[2*(AB2 + BB2)];   // ~49 KB
  int tid  = threadIdx.x;
  int lane = tid & 63, w = tid >> 6;
  int row0 = blockIdx.x * BM;

  // A staging: thread -> (row r, 16B-seg s16): 256B contiguous per row per step
  int r   = tid >> 4;                // 0..31
  int s16 = tid & 15;                // 0..15
  const short* ap = adjBF + (size_t)(row0 + r)*KDIM + s16*8;
  int AwOff = s16*APG + r*16;

  // B staging: thread -> (col nB, pages q2 and q2+8)
  int nB = tid & 63;
  int q2 = tid >> 6;                 // 0..7
  const short* bp = gT + (size_t)nB*KDIM + q2*8;
  int BwOffA = q2*BPG + nB*16;
  int BwOffB = (q2+8)*BPG + nB*16;

  int wm = w >> 2, wn = w & 3;
  int fr = lane & 15, fk = lane >> 4;
  int ArdOff = (wm*16 + fr)*16;
  int BrdOff = (wn*16 + fr)*16;

  f32x4 acc = {0.f,0.f,0.f,0.f};

  // prologue: stage step 0, preload step 1
  short8 aR = *(const short8*)(ap);
  short8 bR0 = *(const short8*)(bp);
  short8 bR1 = *(const short8*)(bp + 64);
  *(short8*)(lds + AwOff) = aR;
  *(short8*)(lds + 2*AB2 + BwOffA) = bR0;
  *(short8*)(lds + 2*AB2 + BwOffB) = bR1;
  aR  = *(const short8*)(ap + BKB);
  bR0 = *(const short8*)(bp + BKB);
  bR1 = *(const short8*)(bp + BKB + 64);
  __syncthreads();

  for (int i = 0; i < NSTEPB; i++){
    const char* Ab = lds + (i & 1)*AB2;
    const char* Bb = lds + 2*AB2 + (i & 1)*BB2;
    short8 af[4], bf[4];
    #pragma unroll
    for(int kb = 0; kb < 4; kb++){
      af[kb] = *(const short8*)(Ab + (kb*4 + fk)*APG + ArdOff);
      bf[kb] = *(const short8*)(Bb + (kb*4 + fk)*BPG + BrdOff);
    }
    short8 aN, bN0, bN1;
    if (i + 2 < NSTEPB){
      aN  = *(const short8*)(ap + (size_t)(i+2)*BKB);
      bN0 = *(const short8*)(bp + (size_t)(i+2)*BKB);
      bN1 = *(const short8*)(bp + (size_t)(i+2)*BKB + 64);
    }
    if (i + 1 < NSTEPB){
      char* Aw = lds + ((i+1) & 1)*AB2;
      char* Bw = lds + 2*AB2 + ((i+1) & 1)*BB2;
      *(short8*)(Aw + AwOff) = aR;
      *(short8*)(Bw + BwOffA) = bR0;
      *(short8*)(Bw + BwOffB) = bR1;
    }
    #pragma unroll
    for(int kb = 0; kb < 4; kb++){
      acc = __builtin_amdgcn_mfma_f32_16x16x32_bf16(af[kb], bf[kb], acc, 0, 0, 0);
    }
    aR = aN; bR0 = bN0; bR1 = bN1;
    __syncthreads();
  }

  float* ob = agg + (size_t)(row0 + wm*16)*64 + wn*16;
  #pragma unroll
  for(int q = 0; q < 4; q++){
    ob[(size_t)((lane >> 4)*4 + q)*64 + (lane & 15)] = acc[q];
  }
}

// ---- fused: (layer1: rinv compute/store) + postagg chain -> h
template<int LAYER>
__global__ __launch_bounds__(256) void k_post(const float* __restrict__ agg,
                                              const float* __restrict__ prsum,
                                              float* __restrict__ rinv,
                                              float* __restrict__ h){
  int tid = threadIdx.x; int lane = tid & 63;
  int row = blockIdx.x*4 + (tid >> 6);
  float s = agg[(size_t)row*64 + lane];
  float ri;
  if (LAYER == 1){
    float rsum = prsum[row];
    ri = (rsum != 0.f) ? 1.f/rsum : 0.f;
    if (lane == 0) rinv[row] = ri;
  } else {
    ri = rinv[row];
  }
  float a  = s * ri;
  float at = lane ? a : 0.f;
  float ss = wredsum(at*at);
  float un = fmaxf(sqrtf(ss), MINN);
  float sc = sinhf(un)/un;
  float e  = sc*at;
  float s2 = wredsum(e*e);
  float x0 = sqrtf(fmaxf(1.f+s2, EPSF));
  float yn = fmaxf(sqrtf(s2), MINN);
  float th = fmaxf(x0, 1.f+EPSF);
  float lt = lane ? acoshf(th)*e/yn : 0.f;
  float rl = fmaxf(lt, 0.f);
  float s3 = wredsum(rl*rl);
  float rn = fmaxf(sqrtf(s3), MINN);
  float sc2= sinhf(rn)/rn;
  float e2 = sc2*rl;
  float s4 = wredsum(e2*e2);
  float h0 = sqrtf(fmaxf(1.f+s4, EPSF));
  h[(size_t)row*64 + lane] = lane ? e2 : h0;
}

extern "C" void kernel_launch(void* const* d_in, const int* in_sizes, int n_in,
                              void* d_out, int out_size, void* d_ws, size_t ws_size,
                              hipStream_t stream){
  const float* x   = (const float*)d_in[0];
  const float* adj = (const float*)d_in[1];
  const float* W1  = (const float*)d_in[2];
  const float* b1  = (const float*)d_in[3];
  const float* W2  = (const float*)d_in[4];
  const float* b2  = (const float*)d_in[5];
  float* out = (float*)d_out;
  float* h1  = out;
  float* h2  = out + (size_t)NROWS*64;

  float* wsf   = (float*)d_ws;
  float* gbuf  = wsf;                              // N*64 f32
  float* aggb  = gbuf  + (size_t)NROWS*64;         // N*64 f32
  float* prsum = aggb  + (size_t)NROWS*64;         // N
  float* rinv  = prsum + NROWS;                    // N
  float* ubs   = rinv  + NROWS;                    // 128
  short* gT    = (short*)(ubs + 128);              // 64*N bf16 (2 MB)
  short* adjBF = gT + (size_t)64*KDIM;             // N*N bf16 (537 MB)

  k_bias<<<1, 128, 0, stream>>>(b1, b2, ubs);
  // layer 1
  k_linear<0><<<NROWS/4, 256, 0, stream>>>(x, W1, ubs, gbuf);
  k_tr<<<NROWS/64, 256, 0, stream>>>(gbuf, gT);
  k_matmul1<<<NROWS/BM, 512, 0, stream>>>(adj, gT, aggb, prsum, adjBF);
  k_post<1><<<NROWS/4, 256, 0, stream>>>(aggb, prsum, rinv, h1);
  // layer 2
  k_linear<1><<<NROWS/4, 256, 0, stream>>>(h1, W2, ubs + 64, gbuf);
  k_tr<<<NROWS/64, 256, 0, stream>>>(gbuf, gT);
  k_matmul2<<<NROWS/BM, 512, 0, stream>>>(adjBF, gT, aggb);
  k_post<2><<<NROWS/4, 256, 0, stream>>>(aggb, prsum, rinv, h2);
}

// Round 9
// 597.428 us; speedup vs baseline: 1.3294x; 1.3294x over previous
//
#include <hip/hip_runtime.h>
#include <cstdint>
#include <cstddef>

#define NROWS 16384
#define KDIM  16384
#define EPSF  1e-7f
#define MINN  1e-15f
#define MAXN  1e6f
#define KSPLIT 4
#define KRANGE (KDIM/KSPLIT)   /* 4096 */
#define BM    64               /* rows per block */
#define BK    64               /* K per step */
#define NSTEP (KRANGE/BK)      /* 64 */
#define PG    1040             /* A page: 64 slots*16B + 16B pad */
#define ABUF  (8*PG)           /* 8320 */

typedef __attribute__((ext_vector_type(8)))  short short8;
typedef __attribute__((ext_vector_type(4)))  float f32x4;
typedef __attribute__((ext_vector_type(16))) float f32x16;

__device__ __forceinline__ short f2bf(float f){
  union { float f; unsigned u; } c; c.f = f;
  unsigned u = c.u;
  unsigned r = (u + 0x7FFFu + ((u >> 16) & 1u)) >> 16;   // RNE
  return (short)r;
}

__device__ __forceinline__ float wredsum(float v){
  v += __shfl_xor(v, 1);
  v += __shfl_xor(v, 2);
  v += __shfl_xor(v, 4);
  v += __shfl_xor(v, 8);
  v += __shfl_xor(v, 16);
  v += __shfl_xor(v, 32);
  return v;
}

// ---- ub = logmap0(proj(expmap0(proj_tan0(b)))) for b1 (wave0) and b2 (wave1)
__global__ __launch_bounds__(128) void k_bias(const float* __restrict__ b1,
                                              const float* __restrict__ b2,
                                              float* __restrict__ ub){
  int w = threadIdx.x >> 6, l = threadIdx.x & 63;
  const float* b = w ? b2 : b1;
  float bv = b[l];
  float tb = l ? bv : 0.f;
  float s  = wredsum(tb*tb);
  float xn = fmaxf(sqrtf(s), MINN);
  float sc = sinhf(xn)/xn;
  float e  = sc*tb;
  float s2 = wredsum(e*e);
  float x0 = sqrtf(fmaxf(1.f+s2, EPSF));
  float yn = fmaxf(sqrtf(s2), MINN);
  float th = fmaxf(x0, 1.f+EPSF);
  float u  = l ? acoshf(th)*e/yn : 0.f;
  ub[w*64 + l] = u;
}

// ---- per-row linear + mobius bias chain -> g
template<int MODE>
__global__ __launch_bounds__(256) void k_linear(const float* __restrict__ in,
                                                const float* __restrict__ W,
                                                const float* __restrict__ ub,
                                                float* __restrict__ g){
  __shared__ float Wt[64*65];
  int tid = threadIdx.x;
  for(int idx = tid; idx < 4096; idx += 256){
    int j = idx >> 6, k = idx & 63;
    Wt[k*65 + j] = W[idx];
  }
  __syncthreads();
  int lane = tid & 63;
  int row  = blockIdx.x*4 + (tid >> 6);
  float v = in[(size_t)row*64 + lane];
  float lx;
  if (MODE == 0){
    float t  = lane ? v : 0.f;
    float s  = wredsum(t*t);
    float tn = fmaxf(sqrtf(s), MINN);
    float sc = sinhf(tn)/tn;
    float e  = sc*t;
    float s2 = wredsum(e*e);
    float x0 = sqrtf(fmaxf(1.f+s2, EPSF));
    float yn = fmaxf(sqrtf(s2), MINN);
    float th = fmaxf(x0, 1.f+EPSF);
    lx = lane ? acoshf(th)*e/yn : 0.f;
  } else {
    float t  = lane ? v : 0.f;
    float s2 = wredsum(t*t);
    float x0 = __shfl(v, 0);
    float yn = fmaxf(sqrtf(s2), MINN);
    float th = fmaxf(x0, 1.f+EPSF);
    lx = lane ? acoshf(th)*t/yn : 0.f;
  }
  float mv = 0.f;
  #pragma unroll
  for(int k = 0; k < 64; k++){
    mv = fmaf(__shfl(lx, k), Wt[k*65 + lane], mv);
  }
  float u  = lane ? mv : 0.f;
  float s  = wredsum(u*u);
  float un = fmaxf(sqrtf(s), MINN);
  float sc = sinhf(un)/un;
  float e  = sc*u;
  float s2 = wredsum(e*e);
  float r0 = sqrtf(fmaxf(1.f+s2, EPSF));
  float ubt   = lane ? ub[lane] : 0.f;
  float yn    = fmaxf(sqrtf(s2), MINN);
  float yhat  = e/yn;
  float alpha = wredsum(yhat*ubt);
  float w     = ubt - alpha*(1.f - r0)*yhat;
  float ux    = wredsum(e*w);
  float v0    = ux / fmaxf(r0, EPSF);
  float md    = wredsum(w*w) - v0*v0;
  float normu = fminf(sqrtf(fmaxf(md, EPSF)), MAXN);
  float th2   = fmaxf(normu, MINN);
  float ch    = coshf(th2);
  float shq   = sinhf(th2)/th2;
  float ov    = ch*(lane ? e : r0) + shq*(lane ? w : v0);
  float ot    = lane ? ov : 0.f;
  float s3    = wredsum(ot*ot);
  float o0    = sqrtf(fmaxf(1.f+s3, EPSF));
  float yn2 = fmaxf(sqrtf(s3), MINN);
  float th3 = fmaxf(o0, 1.f+EPSF);
  float gv  = lane ? acoshf(th3)*ot/yn2 : 0.f;
  g[(size_t)row*64 + lane] = gv;
}

// ---- transpose + bf16 convert: g[N][64] f32 -> gT[64][N] bf16
__global__ __launch_bounds__(256) void k_tr(const float* __restrict__ g,
                                            short* __restrict__ gT){
  __shared__ float t[64][65];
  int tid = threadIdx.x;
  int b   = blockIdx.x;
  int r   = tid >> 2;
  int c0  = (tid & 3)*16;
  const float* src = g + ((size_t)b*64 + r)*64 + c0;
  #pragma unroll
  for(int i = 0; i < 4; i++){
    float4 v = *(const float4*)(src + i*4);
    t[r][c0 + i*4 + 0] = v.x; t[r][c0 + i*4 + 1] = v.y;
    t[r][c0 + i*4 + 2] = v.z; t[r][c0 + i*4 + 3] = v.w;
  }
  __syncthreads();
  int n   = tid >> 2;
  int seg = tid & 3;
  short8 p0, p1;
  #pragma unroll
  for(int j = 0; j < 8; j++) p0[j] = f2bf(t[seg*16 + j][n]);
  #pragma unroll
  for(int j = 0; j < 8; j++) p1[j] = f2bf(t[seg*16 + 8 + j][n]);
  short* dst = gT + (size_t)n*KDIM + b*64 + seg*16;
  *(short8*)(dst)     = p0;
  *(short8*)(dst + 8) = p1;
}

// ---- 32x32x16 MFMA split-K matmul: A-only LDS (dbuf, 1 barrier/step), B direct
// from L2-resident gT to registers. pagg[ks] = adj[:,kr] @ g[kr,:]; rowsums if FIRST.
template<bool FIRST>
__global__ __launch_bounds__(256, 4) void k_matmul(const float* __restrict__ adj,
                                                   const short* __restrict__ gT,
                                                   float* __restrict__ pagg,
                                                   float* __restrict__ prsum){
  __shared__ __align__(16) char Alds[2*ABUF];   // 16.6 KB
  int tid  = threadIdx.x;
  int lane = tid & 63, w = tid >> 6;
  int rb   = blockIdx.x;               // rb in LOW grid bits (R2-proven)
  int ks   = blockIdx.y;
  int row0 = rb*BM;
  size_t k0 = (size_t)ks * KRANGE;

  // staging role: thread -> (row sr, k16-seg sseg); 64B contiguous per thread
  int sr   = tid >> 2;                 // 0..63
  int sseg = tid & 3;                  // 0..3
  const float4* ap = (const float4*)(adj + (size_t)(row0 + sr)*KDIM + k0 + sseg*16);
  int AwOff0 = (sseg*2)*PG   + sr*16;  // k-octet page 2*sseg
  int AwOff1 = (sseg*2+1)*PG + sr*16;  // k-octet page 2*sseg+1

  // compute role: wave (wm,wn) -> rows wm*32..+32, cols wn*32..+32
  int wm = w >> 1, wn = w & 1;
  int lr = lane & 31, lh = lane >> 5;
  int ArdOff = lh*PG + (wm*32 + lr)*16;          // chunk c adds 2c*PG
  const short* bp = gT + (size_t)(wn*32 + lr)*KDIM + k0 + lh*8;

  f32x16 acc;
  #pragma unroll
  for(int q = 0; q < 16; q++) acc[q] = 0.f;
  float rs = 0.f;

  float4 aR[4], aN[4];
  short8 bC[4], bN[4];

  // prologue: load+stage step 0; preload A(1), B(0)
  #pragma unroll
  for(int q = 0; q < 4; q++) aR[q] = ap[q];
  {
    if (FIRST){
      #pragma unroll
      for(int q = 0; q < 4; q++) rs += aR[q].x + aR[q].y + aR[q].z + aR[q].w;
    }
    short8 lo = { f2bf(aR[0].x), f2bf(aR[0].y), f2bf(aR[0].z), f2bf(aR[0].w),
                  f2bf(aR[1].x), f2bf(aR[1].y), f2bf(aR[1].z), f2bf(aR[1].w) };
    short8 hi = { f2bf(aR[2].x), f2bf(aR[2].y), f2bf(aR[2].z), f2bf(aR[2].w),
                  f2bf(aR[3].x), f2bf(aR[3].y), f2bf(aR[3].z), f2bf(aR[3].w) };
    *(short8*)(Alds + AwOff0) = lo;
    *(short8*)(Alds + AwOff1) = hi;
  }
  #pragma unroll
  for(int q = 0; q < 4; q++) aR[q] = ap[16 + q];          // step 1
  #pragma unroll
  for(int c = 0; c < 4; c++) bC[c] = *(const short8*)(bp + c*16);   // step 0
  __syncthreads();

  for (int i = 0; i < NSTEP; i++){
    const char* Ab = Alds + (i & 1)*ABUF;
    short8 af0 = *(const short8*)(Ab + ArdOff);
    short8 af1 = *(const short8*)(Ab + ArdOff + 2*PG);
    short8 af2 = *(const short8*)(Ab + ArdOff + 4*PG);
    short8 af3 = *(const short8*)(Ab + ArdOff + 6*PG);
    if (i + 2 < NSTEP){
      #pragma unroll
      for(int q = 0; q < 4; q++) aN[q] = ap[(i+2)*16 + q];
    }
    if (i + 1 < NSTEP){
      #pragma unroll
      for(int c = 0; c < 4; c++) bN[c] = *(const short8*)(bp + (size_t)(i+1)*BK + c*16);
    }
    acc = __builtin_amdgcn_mfma_f32_32x32x16_bf16(af0, bC[0], acc, 0, 0, 0);
    acc = __builtin_amdgcn_mfma_f32_32x32x16_bf16(af1, bC[1], acc, 0, 0, 0);
    acc = __builtin_amdgcn_mfma_f32_32x32x16_bf16(af2, bC[2], acc, 0, 0, 0);
    acc = __builtin_amdgcn_mfma_f32_32x32x16_bf16(af3, bC[3], acc, 0, 0, 0);
    if (i + 1 < NSTEP){
      char* Aw = Alds + ((i+1) & 1)*ABUF;
      if (FIRST){
        #pragma unroll
        for(int q = 0; q < 4; q++) rs += aR[q].x + aR[q].y + aR[q].z + aR[q].w;
      }
      short8 lo = { f2bf(aR[0].x), f2bf(aR[0].y), f2bf(aR[0].z), f2bf(aR[0].w),
                    f2bf(aR[1].x), f2bf(aR[1].y), f2bf(aR[1].z), f2bf(aR[1].w) };
      short8 hi = { f2bf(aR[2].x), f2bf(aR[2].y), f2bf(aR[2].z), f2bf(aR[2].w),
                    f2bf(aR[3].x), f2bf(aR[3].y), f2bf(aR[3].z), f2bf(aR[3].w) };
      *(short8*)(Aw + AwOff0) = lo;
      *(short8*)(Aw + AwOff1) = hi;
    }
    #pragma unroll
    for(int q = 0; q < 4; q++) aR[q] = aN[q];
    #pragma unroll
    for(int c = 0; c < 4; c++) bC[c] = bN[c];
    __syncthreads();
  }

  if (FIRST){
    rs += __shfl_xor(rs, 1);
    rs += __shfl_xor(rs, 2);
    if ((tid & 3) == 0) prsum[(size_t)ks*NROWS + row0 + sr] = rs;
  }
  // C write: 32x32 D layout (m74): col = lane&31, row = (q&3) + 8*(q>>2) + 4*(lane>>5)
  float* ob = pagg + ((size_t)ks*NROWS + row0 + wm*32)*64 + wn*32;
  #pragma unroll
  for(int q = 0; q < 16; q++){
    int rl = (q & 3) + 8*(q >> 2) + 4*lh;
    ob[(size_t)rl*64 + lr] = acc[q];
  }
}

// ---- fused: split-K reduce + (layer1: rinv compute/store) + postagg chain -> h
template<int LAYER>
__global__ __launch_bounds__(256) void k_post(const float* __restrict__ pagg,
                                              const float* __restrict__ prsum,
                                              float* __restrict__ rinv,
                                              float* __restrict__ h){
  int tid = threadIdx.x; int lane = tid & 63;
  int row = blockIdx.x*4 + (tid >> 6);
  float s = 0.f;
  #pragma unroll
  for(int ks = 0; ks < KSPLIT; ks++) s += pagg[(size_t)ks*NROWS*64 + (size_t)row*64 + lane];
  float ri;
  if (LAYER == 1){
    float rsum = 0.f;
    #pragma unroll
    for(int ks = 0; ks < KSPLIT; ks++) rsum += prsum[(size_t)ks*NROWS + row];
    ri = (rsum != 0.f) ? 1.f/rsum : 0.f;
    if (lane == 0) rinv[row] = ri;
  } else {
    ri = rinv[row];
  }
  float a  = s * ri;
  float at = lane ? a : 0.f;
  float ss = wredsum(at*at);
  float un = fmaxf(sqrtf(ss), MINN);
  float sc = sinhf(un)/un;
  float e  = sc*at;
  float s2 = wredsum(e*e);
  float x0 = sqrtf(fmaxf(1.f+s2, EPSF));
  float yn = fmaxf(sqrtf(s2), MINN);
  float th = fmaxf(x0, 1.f+EPSF);
  float lt = lane ? acoshf(th)*e/yn : 0.f;
  float rl = fmaxf(lt, 0.f);
  float s3 = wredsum(rl*rl);
  float rn = fmaxf(sqrtf(s3), MINN);
  float sc2= sinhf(rn)/rn;
  float e2 = sc2*rl;
  float s4 = wredsum(e2*e2);
  float h0 = sqrtf(fmaxf(1.f+s4, EPSF));
  h[(size_t)row*64 + lane] = lane ? e2 : h0;
}

extern "C" void kernel_launch(void* const* d_in, const int* in_sizes, int n_in,
                              void* d_out, int out_size, void* d_ws, size_t ws_size,
                              hipStream_t stream){
  const float* x   = (const float*)d_in[0];
  const float* adj = (const float*)d_in[1];
  const float* W1  = (const float*)d_in[2];
  const float* b1  = (const float*)d_in[3];
  const float* W2  = (const float*)d_in[4];
  const float* b2  = (const float*)d_in[5];
  float* out = (float*)d_out;
  float* h1  = out;
  float* h2  = out + (size_t)NROWS*64;

  float* wsf   = (float*)d_ws;
  float* gbuf  = wsf;                              // N*64 f32
  float* pagg  = gbuf  + (size_t)NROWS*64;         // KSPLIT*N*64 f32 (16 MB)
  float* prsum = pagg  + (size_t)KSPLIT*NROWS*64;  // KSPLIT*N
  float* rinv  = prsum + (size_t)KSPLIT*NROWS;     // N
  float* ubs   = rinv  + NROWS;                    // 128
  short* gT    = (short*)(ubs + 128);              // 64*N bf16 (2 MB)

  dim3 gm(NROWS/BM, KSPLIT);                       // rb in LOW bits

  k_bias<<<1, 128, 0, stream>>>(b1, b2, ubs);
  // layer 1
  k_linear<0><<<NROWS/4, 256, 0, stream>>>(x, W1, ubs, gbuf);
  k_tr<<<NROWS/64, 256, 0, stream>>>(gbuf, gT);
  k_matmul<true><<<gm, 256, 0, stream>>>(adj, gT, pagg, prsum);
  k_post<1><<<NROWS/4, 256, 0, stream>>>(pagg, prsum, rinv, h1);
  // layer 2
  k_linear<1><<<NROWS/4, 256, 0, stream>>>(h1, W2, ubs + 64, gbuf);
  k_tr<<<NROWS/64, 256, 0, stream>>>(gbuf, gT);
  k_matmul<false><<<gm, 256, 0, stream>>>(adj, gT, pagg, prsum);
  k_post<2><<<NROWS/4, 256, 0, stream>>>(pagg, prsum, rinv, h2);
}